// Round 6
// baseline (2058.312 us; speedup 1.0000x reference)
//
#include <hip/hip_runtime.h>

#define NS 8192
#define L  50

typedef unsigned short u16;
typedef unsigned int   u32;
typedef __attribute__((ext_vector_type(8))) __bf16 bf16x8;
typedef __attribute__((ext_vector_type(4))) float  f32x4;

// ---------------- LDS layout (bytes) ----------------
// X [64][328] bf16 lives P1..fused-loop (dies at sync2).
// Tt [160][68] aliases X (written post-sync2 by waves 0,1; read in P5 by 2,3).
// T2t [64][68] aliases Tt (P6). red aliases at 9216 (post-sync6).
// H1 [64][168] at 21760 (overlaps dead X tail). M (stride 72) at 43264; diag aliases M.
#define OFF_X    0
#define OFF_TT   0
#define OFF_T2T  0
#define OFF_RED  9216     // red f32 [64][20] = 5120 -> 14336
#define OFF_H1   21760    // H1 bf16 [64][168] = 21504 -> 43264
#define OFF_M    43264    // M bf16 [64][72] = 9216 -> 52480
#define OFF_DIAG 43264    // diag f32[64] (dead before M written)
#define OFF_WID  52480
#define OFF_CLO  52736
#define OFF_CHI  52992
#define OFF_RDEG 53248
#define SMEM_SZ  53504    // 3 blocks/CU

#define XSTR  328   // 656B rows: ==4 mod 32 dword-banks -> 2-way (free)
#define TSTR  68    // 136B rows, 8B aligned
#define H1STR 168   // 336B rows, 16B aligned
#define MSTR  72    // 144B rows, 16B aligned -> b128 frag loads
#define RSTR  20    // red row stride (f32), 80B -> b128-aligned

// padded weight tables in ws
#define W1_ROWS 320   // rows [0,150)=W1n (col j), [160,310)=W1s; rest 0
#define W1_KP   328
#define W2_ROWS 128   // rows [0,64)=W2s, [64,128)=W2n
#define W2_KP   168
#define W1SZ (W1_ROWS * W1_KP)
#define W2SZ (W2_ROWS * W2_KP)

__device__ __forceinline__ u16 f2bf(float f) {
  u32 u = __float_as_uint(f);
  u += 0x7fffu + ((u >> 16) & 1u);   // RNE (epilogues + prep)
  return (u16)(u >> 16);
}
__device__ __forceinline__ f32x4 mfma16(bf16x8 a, bf16x8 b, f32x4 c) {
  return __builtin_amdgcn_mfma_f32_16x16x32_bf16(a, b, c, 0, 0, 0);
}
__device__ __forceinline__ uint2 pack4bf(f32x4 c) {
  uint2 p;
  p.x = (u32)f2bf(c[0]) | ((u32)f2bf(c[1]) << 16);
  p.y = (u32)f2bf(c[2]) | ((u32)f2bf(c[3]) << 16);
  return p;
}
union BF8U { bf16x8 v; uint4 u; };
__device__ __forceinline__ bf16x8 ld_bf8_b64pair(const u16* p) {
  uint2 a = *(const uint2*)p;
  uint2 b = *(const uint2*)(p + 4);
  BF8U r; r.u = make_uint4(a.x, a.y, b.x, b.y);
  return r.v;
}

struct GParams {
  const int* words; const int* syn_words; const int* syn_adj;
  const float* embed;
  const float* sem_b1; const float* sem_b2; const float* sem_gw; const float* sem_gb;
  const float* syn_b1; const float* syn_b2; const float* syn_gw; const float* syn_gb;
  const u16* w1t_sem; const u16* w1t_syn; const u16* w2t_sem; const u16* w2t_syn;
  float* semf; float* synf;
};

// One block per (sentence, graph). [0,NS)=semantic, [NS,2NS)=syntax.
__global__ __launch_bounds__(256, 3) void sage_kernel(GParams P) {
  __shared__ __align__(16) char smem[SMEM_SZ];
  int*   wid   = (int*)(smem + OFF_WID);
  u32*   clo   = (u32*)(smem + OFF_CLO);
  u32*   chi   = (u32*)(smem + OFF_CHI);
  float* rdegp = (float*)(smem + OFF_RDEG);
  float* diag  = (float*)(smem + OFF_DIAG);

  const int tid  = threadIdx.x;
  const int lane = tid & 63;
  const int w    = tid >> 6;
  const int ln   = lane & 15;
  const int quad = lane >> 4;

  const bool semg = (blockIdx.x < NS);
  const int  n    = semg ? blockIdx.x : (blockIdx.x - NS);

  const int*   wsrc = semg ? P.words   : P.syn_words;
  const u16*   W1T  = semg ? P.w1t_sem : P.w1t_syn;
  const u16*   W2T  = semg ? P.w2t_sem : P.w2t_syn;
  const float* b1g  = semg ? P.sem_b1  : P.syn_b1;
  const float* b2g  = semg ? P.sem_b2  : P.syn_b2;
  const float* gw   = semg ? P.sem_gw  : P.syn_gw;
  const float* gb   = semg ? P.sem_gb  : P.syn_gb;
  float* featout    = semg ? P.semf    : P.synf;

  // ---- P1: gather X bf16 [64][328]; 4 lanes/row, direct global word loads ----
  {
    const int r    = w * 16 + (lane >> 2);      // wave w owns rows [16w,16w+16)
    const int part = lane & 3;
    int word = 0;
    if (r < L) word = wsrc[(size_t)n * L + r];
    const float* src = P.embed + (size_t)word * 300;
    u16* xrow = (u16*)(smem + OFF_X) + r * XSTR;
    #pragma unroll
    for (int k = 0; k < 11; ++k) {
      const int s = part + 4 * k;               // 8-elem slot; 41 slots = 328
      if (s < 41) {
        uint4 out = make_uint4(0u, 0u, 0u, 0u);
        if (word > 0) {
          const int e = s * 8;
          if (e < 300) {
            float4 f = *(const float4*)(src + e);
            u32 ax = __float_as_uint(f.x) + 0x8000u;
            u32 ay = __float_as_uint(f.y) + 0x8000u;
            u32 az = __float_as_uint(f.z) + 0x8000u;
            u32 aw = __float_as_uint(f.w) + 0x8000u;
            out.x = (ax >> 16) | (ay & 0xffff0000u);
            out.y = (az >> 16) | (aw & 0xffff0000u);
          }
          if (e + 4 < 300) {
            float4 f = *(const float4*)(src + e + 4);
            u32 ax = __float_as_uint(f.x) + 0x8000u;
            u32 ay = __float_as_uint(f.y) + 0x8000u;
            u32 az = __float_as_uint(f.z) + 0x8000u;
            u32 aw = __float_as_uint(f.w) + 0x8000u;
            out.z = (ax >> 16) | (ay & 0xffff0000u);
            out.w = (az >> 16) | (aw & 0xffff0000u);
          }
        }
        *(uint4*)(xrow + s * 8) = out;
      }
    }
    if (tid < 64) {
      wid[tid] = (tid < L) ? wsrc[(size_t)n * L + tid] : 0;
      clo[tid] = 0u; chi[tid] = 0u;
    }
  }
  __syncthreads();   // sync1: X + wid + zeroed masks visible

  const f32x4 z4 = {0.f, 0.f, 0.f, 0.f};

  // syntax masks: independent of the fused loop, do now (no extra barrier)
  if (!semg) {
    const int* abase = P.syn_adj + (size_t)n * (L * L);
    for (int v = w; v < L; v += 4) {
      int val = (lane < L) ? abase[lane * L + v] : 0;
      unsigned long long m = __ballot(val != 0);
      if (lane == 0) { clo[v] = (u32)m; chi[v] = (u32)(m >> 32); }
    }
  }

  // ---- fused Gram + GEMM1 k-loop: X frags read ONCE ----
  // waves 0,1 -> 10 t-tiles (D[v][j]); waves 2,3 -> 10 s-tiles (D[j][v], swapped)
  f32x4 acc[5][4];
  f32x4 g[4] = {z4, z4, z4, z4};
  #pragma unroll
  for (int i = 0; i < 5; ++i)
    #pragma unroll
    for (int m = 0; m < 4; ++m) acc[i][m] = z4;
  {
    const char* xb = smem + OFF_X;
    const u16* W1p[5];
    #pragma unroll
    for (int i = 0; i < 5; ++i) {
      const int base = (w < 2) ? (w * 5 + i) : (10 + (w - 2) * 5 + i);
      W1p[i] = W1T + (size_t)(base * 16 + ln) * W1_KP + quad * 8;
    }
    const int arow = (w * 16 + ln) * (XSTR * 2) + quad * 16;
    for (int kk = 0; kk < 10; ++kk) {
      const int xo = quad * 16 + kk * 64;
      bf16x8 x[4];
      #pragma unroll
      for (int m = 0; m < 4; ++m)
        x[m] = *(const bf16x8*)(xb + (m * 16 + ln) * (XSTR * 2) + xo);
      bf16x8 bw[5];
      #pragma unroll
      for (int i = 0; i < 5; ++i) bw[i] = *(const bf16x8*)(W1p[i] + kk * 32);
      if (semg) {
        bf16x8 a = *(const bf16x8*)(xb + arow + kk * 64);
        #pragma unroll
        for (int nt = 0; nt < 4; ++nt) g[nt] = mfma16(a, x[nt], g[nt]);
      }
      if (w < 2) {
        #pragma unroll
        for (int i = 0; i < 5; ++i)
          #pragma unroll
          for (int m = 0; m < 4; ++m) acc[i][m] = mfma16(x[m], bw[i], acc[i][m]);
      } else {
        #pragma unroll
        for (int i = 0; i < 5; ++i)
          #pragma unroll
          for (int m = 0; m < 4; ++m) acc[i][m] = mfma16(bw[i], x[m], acc[i][m]);
      }
    }
  }
  // diag (u==v requires nt==w, ln in [quad*4, quad*4+4))
  if (semg) {
    const int r = ln - quad * 4;
    if (r >= 0 && r < 4) {
      #pragma unroll
      for (int nt = 0; nt < 4; ++nt) {
        if (nt == w) {
          float val = (r == 0) ? g[nt][0] : (r == 1) ? g[nt][1]
                    : (r == 2) ? g[nt][2] : g[nt][3];
          diag[w * 16 + ln] = val;
        }
      }
    }
  }
  __syncthreads();   // sync2: X dead, diag visible

  // ---- threshold (sem, inline rsqrt) -- concurrent with P4 Tt writes ----
  if (semg) {
    const int ubase = w * 16 + quad * 4;
    float ru[4]; int uok[4];
    #pragma unroll
    for (int r = 0; r < 4; ++r) {
      ru[r] = rsqrtf(fmaxf(diag[ubase + r], 1e-12f));
      uok[r] = wid[ubase + r] > 0;
    }
    #pragma unroll
    for (int nt = 0; nt < 4; ++nt) {
      const int v = nt * 16 + ln;
      const float rv = rsqrtf(fmaxf(diag[v], 1e-12f));
      const bool vok = wid[v] > 0;
      u32 nib = 0u;
      #pragma unroll
      for (int r = 0; r < 4; ++r) {
        float c = g[nt][r] * ru[r] * rv;
        if (vok && uok[r] && c > 0.7f) nib |= (1u << r);
      }
      if (nib) {
        if (ubase < 32) atomicOr(&clo[v], nib << ubase);
        else            atomicOr(&chi[v], nib << (ubase - 32));
      }
    }
  }
  // ---- P4: waves 0,1 write Tt[j][u] into dead-X region ----
  if (w < 2) {
    u16* tt = (u16*)(smem + OFF_TT);
    #pragma unroll
    for (int i = 0; i < 5; ++i) {
      const int gg = w * 5 + i;
      #pragma unroll
      for (int m = 0; m < 4; ++m) {
        const int v0 = m * 16 + quad * 4;
        *(uint2*)(tt + (gg * 16 + ln) * TSTR + v0) = pack4bf(acc[i][m]);
      }
    }
  }
  __syncthreads();   // sync3: masks final + Tt visible

  // ---- M build + rdeg ----
  if (tid < 64) {
    int dg = __popc(clo[tid]) + __popc(chi[tid]);
    rdegp[tid] = 1.0f / (float)(dg > 0 ? dg : 1);
  }
  {
    const int v = lane, half = w;
    const u32 src = (half < 2) ? clo[v] : chi[v];
    const int sh = (half & 1) * 16;
    u16* Mrow = (u16*)(smem + OFF_M) + v * MSTR + half * 16;
    #pragma unroll
    for (int c = 0; c < 4; ++c) {
      uint2 pk;
      u32 b0 = (src >> (sh + 4 * c + 0)) & 1u;
      u32 b1 = (src >> (sh + 4 * c + 1)) & 1u;
      u32 b2 = (src >> (sh + 4 * c + 2)) & 1u;
      u32 b3 = (src >> (sh + 4 * c + 3)) & 1u;
      pk.x = (b0 ? 0x3F80u : 0u) | (b1 ? 0x3F800000u : 0u);
      pk.y = (b2 ? 0x3F80u : 0u) | (b3 ? 0x3F800000u : 0u);
      *(uint2*)(Mrow + 4 * c) = pk;
    }
  }
  __syncthreads();   // sync4: M + rdeg visible

  float rd[4];
  #pragma unroll
  for (int vt = 0; vt < 4; ++vt) rd[vt] = rdegp[vt * 16 + ln];

  // hoisted M fragments (b128, MSTR=72) -- reused by agg1 AND agg2
  bf16x8 mb0[4], mb1[4];
  {
    const u16* Mp = (const u16*)(smem + OFF_M);
    #pragma unroll
    for (int vt = 0; vt < 4; ++vt) {
      mb0[vt] = *(const bf16x8*)(Mp + (vt * 16 + ln) * MSTR + quad * 8);
      mb1[vt] = *(const bf16x8*)(Mp + (vt * 16 + ln) * MSTR + quad * 8 + 32);
    }
  }

  // ---- P5: waves 2,3: agg1 = Tt x M (D[j][v]); h1 = relu(s+agg*rd+b1) -> H1 ----
  if (w >= 2) {
    const u16* tt = (const u16*)(smem + OFF_TT);
    u16* h1p = (u16*)(smem + OFF_H1);
    #pragma unroll
    for (int i = 0; i < 5; ++i) {
      const int gg = (w - 2) * 5 + i;
      const u16* tb = tt + (gg * 16 + ln) * TSTR + quad * 8;
      bf16x8 ta0 = ld_bf8_b64pair(tb);
      bf16x8 ta1 = ld_bf8_b64pair(tb + 32);
      f32x4 gacc[4] = {z4, z4, z4, z4};
      #pragma unroll
      for (int vt = 0; vt < 4; ++vt) {
        gacc[vt] = mfma16(ta0, mb0[vt], gacc[vt]);
        gacc[vt] = mfma16(ta1, mb1[vt], gacc[vt]);
      }
      const int j0 = gg * 16 + quad * 4;
      float bv[4];
      #pragma unroll
      for (int r = 0; r < 4; ++r) { int j = j0 + r; bv[r] = (j < 150) ? b1g[j] : 0.f; }
      #pragma unroll
      for (int vt = 0; vt < 4; ++vt) {
        const int v = vt * 16 + ln;
        f32x4 hv;
        #pragma unroll
        for (int r = 0; r < 4; ++r)
          hv[r] = fmaxf(acc[i][vt][r] + gacc[vt][r] * rd[vt] + bv[r], 0.f);
        *(uint2*)(h1p + v * H1STR + j0) = pack4bf(hv);
      }
    }
  }
  __syncthreads();   // sync5: all H1 written

  // ---- P6: GEMM2 (s2 swapped in regs; t2 -> T2t self rows) + agg2 ----
  f32x4 h2v[4];
  {
    f32x4 s2acc[4] = {z4, z4, z4, z4};
    f32x4 t2acc[4] = {z4, z4, z4, z4};
    const u16* h1p = (const u16*)(smem + OFF_H1);
    for (int kk = 0; kk < 5; ++kk) {
      const int wo = kk * 32 + quad * 8;
      bf16x8 h[4];
      #pragma unroll
      for (int t4 = 0; t4 < 4; ++t4)
        h[t4] = *(const bf16x8*)(h1p + (t4 * 16 + ln) * H1STR + wo);
      bf16x8 a2  = *(const bf16x8*)(W2T + (size_t)(w * 16 + ln) * W2_KP + wo);
      bf16x8 b2f = *(const bf16x8*)(W2T + (size_t)((4 + w) * 16 + ln) * W2_KP + wo);
      #pragma unroll
      for (int vt = 0; vt < 4; ++vt) {
        s2acc[vt] = mfma16(a2, h[vt], s2acc[vt]);   // D[j2][v]
        t2acc[vt] = mfma16(h[vt], b2f, t2acc[vt]);  // D[v][j2]
      }
    }
    u16* t2t = (u16*)(smem + OFF_T2T);
    #pragma unroll
    for (int m = 0; m < 4; ++m) {
      const int v0 = m * 16 + quad * 4;
      *(uint2*)(t2t + (w * 16 + ln) * TSTR + v0) = pack4bf(t2acc[m]);
    }
    // agg2: A = T2t (self rows, wave-synchronous), B = hoisted mb frags
    f32x4 g2[4] = {z4, z4, z4, z4};
    const u16* t2b = t2t + (w * 16 + ln) * TSTR + quad * 8;
    bf16x8 u0 = ld_bf8_b64pair(t2b);
    bf16x8 u1 = ld_bf8_b64pair(t2b + 32);
    #pragma unroll
    for (int vt = 0; vt < 4; ++vt) {
      g2[vt] = mfma16(u0, mb0[vt], g2[vt]);
      g2[vt] = mfma16(u1, mb1[vt], g2[vt]);
    }
    const int j0q = w * 16 + quad * 4;
    float b2v[4];
    #pragma unroll
    for (int r = 0; r < 4; ++r) b2v[r] = b2g[j0q + r];
    #pragma unroll
    for (int vt = 0; vt < 4; ++vt)
      #pragma unroll
      for (int r = 0; r < 4; ++r)
        h2v[vt][r] = s2acc[vt][r] + g2[vt][r] * rd[vt] + b2v[r];
  }
  __syncthreads();   // sync6: Tt/T2t/H1 reads done -> red region free

  // ---- P7: gate partials -> red[v][RSTR] ----
  {
    const int j0q = w * 16 + quad * 4;
    float gwv[4];
    #pragma unroll
    for (int r = 0; r < 4; ++r) gwv[r] = gw[j0q + r];
    float* redp = (float*)(smem + OFF_RED);
    #pragma unroll
    for (int vt = 0; vt < 4; ++vt) {
      float p = h2v[vt][0] * gwv[0] + h2v[vt][1] * gwv[1]
              + h2v[vt][2] * gwv[2] + h2v[vt][3] * gwv[3];
      redp[(vt * 16 + ln) * RSTR + (w * 4 + quad)] = p;
    }
  }
  __syncthreads();   // sync7

  // ---- P8: masked softmax, redundantly per wave (registers, no barrier) ----
  float attnv;
  {
    const float* redp = (const float*)(smem + OFF_RED) + lane * RSTR;
    f32x4 r0 = *(const f32x4*)(redp);
    f32x4 r1 = *(const f32x4*)(redp + 4);
    f32x4 r2 = *(const f32x4*)(redp + 8);
    f32x4 r3 = *(const f32x4*)(redp + 12);
    float g = gb[0] + r0[0] + r0[1] + r0[2] + r0[3] + r1[0] + r1[1] + r1[2] + r1[3]
            + r2[0] + r2[1] + r2[2] + r2[3] + r3[0] + r3[1] + r3[2] + r3[3];
    const bool val = wid[lane] > 0;
    g = val ? g : -1e30f;
    float mx = g;
    #pragma unroll
    for (int off = 32; off; off >>= 1) mx = fmaxf(mx, __shfl_xor(mx, off));
    float e = val ? __expf(g - mx) : 0.f;
    float ssum = e;
    #pragma unroll
    for (int off = 32; off; off >>= 1) ssum += __shfl_xor(ssum, off);
    attnv = e / ssum;
  }

  // ---- P9: pooled feature out[j2] = sum_v attn[v] h2[v][j2] ----
  {
    float av[4];
    #pragma unroll
    for (int vt = 0; vt < 4; ++vt) av[vt] = __shfl(attnv, vt * 16 + ln);
    float xr[4];
    #pragma unroll
    for (int r = 0; r < 4; ++r) {
      float x = av[0] * h2v[0][r] + av[1] * h2v[1][r]
              + av[2] * h2v[2][r] + av[3] * h2v[3][r];
      #pragma unroll
      for (int off = 1; off < 16; off <<= 1) x += __shfl_xor(x, off);
      xr[r] = x;
    }
    if (ln == 0) {
      const int j0q = w * 16 + quad * 4;
      *(float4*)(featout + (size_t)n * 64 + j0q) = make_float4(xr[0], xr[1], xr[2], xr[3]);
    }
  }
}

// ---------------- merged weight prep: one launch for all 4 tables ----------------
__global__ void prep_all(const float* sem_W1n, const float* sem_W1s,
                         const float* syn_W1n, const float* syn_W1s,
                         const float* sem_W2s, const float* sem_W2n,
                         const float* syn_W2s, const float* syn_W2n,
                         u16* w1t_sem, u16* w1t_syn, u16* w2t_sem, u16* w2t_syn) {
  int idx = blockIdx.x * 256 + threadIdx.x;
  if (idx < 2 * W1SZ) {
    const bool sem = idx < W1SZ;
    const int li = sem ? idx : idx - W1SZ;
    const float* Wn = sem ? sem_W1n : syn_W1n;
    const float* Ws = sem ? sem_W1s : syn_W1s;
    u16* dst = sem ? w1t_sem : w1t_syn;
    int nn = li / W1_KP, k = li - nn * W1_KP;
    float v = 0.f;
    if (k < 300) {
      if (nn < 150) v = Wn[k * 150 + nn];
      else if (nn >= 160 && nn < 310) v = Ws[k * 150 + (nn - 160)];
    }
    dst[li] = f2bf(v);
  } else if (idx < 2 * W1SZ + 2 * W2SZ) {
    int j = idx - 2 * W1SZ;
    const bool sem = j < W2SZ;
    const int li = sem ? j : j - W2SZ;
    const float* Ws = sem ? sem_W2s : syn_W2s;
    const float* Wn = sem ? sem_W2n : syn_W2n;
    u16* dst = sem ? w2t_sem : w2t_syn;
    int nn = li / W2_KP, k = li - nn * W2_KP;
    float v = 0.f;
    if (k < 150) v = (nn < 64) ? Ws[k * 64 + nn] : Wn[k * 64 + (nn - 64)];
    dst[li] = f2bf(v);
  }
}

// ---------------- classifier ----------------
__global__ __launch_bounds__(128) void cls_kernel(const float* semf, const float* synf,
                                                  const float* hsg,
                                                  const float* w1, const float* b1,
                                                  const float* w2, const float* b2,
                                                  float* out) {
  __shared__ float feat[32][192];
  __shared__ float hid[32][132];
  const int r0 = blockIdx.x * 32;
  for (int idx = threadIdx.x; idx < 32 * 192; idx += 128) {
    int r = idx / 192, c = idx % 192;
    float v;
    if (c < 64)        v = semf[(size_t)(r0 + r) * 64 + c];
    else if (c < 128)  v = synf[(size_t)(r0 + r) * 64 + (c - 64)];
    else               v = hsg [(size_t)(r0 + r) * 64 + (c - 128)];
    feat[r][c] = v;
  }
  __syncthreads();
  {
    const int j = threadIdx.x;
    float acc[32];
    float bb = b1[j];
    #pragma unroll
    for (int r = 0; r < 32; ++r) acc[r] = bb;
    for (int k = 0; k < 192; ++k) {
      float ww = w1[(size_t)k * 128 + j];
      #pragma unroll
      for (int r = 0; r < 32; ++r) acc[r] += feat[r][k] * ww;
    }
    #pragma unroll
    for (int r = 0; r < 32; ++r) hid[r][j] = fmaxf(acc[r], 0.0f);
  }
  __syncthreads();
  if (threadIdx.x < 64) {
    const int r = threadIdx.x >> 1, o = threadIdx.x & 1;
    float a = b2[o];
    for (int h = 0; h < 128; ++h) a += hid[r][h] * w2[h * 2 + o];
    out[(size_t)(r0 + r) * 2 + o] = a;
  }
}

extern "C" void kernel_launch(void* const* d_in, const int* in_sizes, int n_in,
                              void* d_out, int out_size, void* d_ws, size_t ws_size,
                              hipStream_t stream) {
  GParams P;
  P.words     = (const int*)d_in[0];
  P.syn_words = (const int*)d_in[1];
  P.syn_adj   = (const int*)d_in[2];
  const float* hsg = (const float*)d_in[3];
  P.embed   = (const float*)d_in[4];
  const float* sem_W1s = (const float*)d_in[5];
  const float* sem_W1n = (const float*)d_in[6];
  P.sem_b1  = (const float*)d_in[7];
  const float* sem_W2s = (const float*)d_in[8];
  const float* sem_W2n = (const float*)d_in[9];
  P.sem_b2  = (const float*)d_in[10];
  P.sem_gw  = (const float*)d_in[11];
  P.sem_gb  = (const float*)d_in[12];
  const float* syn_W1s = (const float*)d_in[13];
  const float* syn_W1n = (const float*)d_in[14];
  P.syn_b1  = (const float*)d_in[15];
  const float* syn_W2s = (const float*)d_in[16];
  const float* syn_W2n = (const float*)d_in[17];
  P.syn_b2  = (const float*)d_in[18];
  P.syn_gw  = (const float*)d_in[19];
  P.syn_gb  = (const float*)d_in[20];
  const float* cls_w1 = (const float*)d_in[21];
  const float* cls_b1 = (const float*)d_in[22];
  const float* cls_w2 = (const float*)d_in[23];
  const float* cls_b2 = (const float*)d_in[24];

  float* semf = (float*)d_ws;                       // [NS][64]
  float* synf = semf + (size_t)NS * 64;             // [NS][64]  (4 MB total)
  u16* w1t_sem = (u16*)((char*)d_ws + (size_t)4 * 1024 * 1024);
  u16* w1t_syn = w1t_sem + W1SZ;
  u16* w2t_sem = w1t_syn + W1SZ;
  u16* w2t_syn = w2t_sem + W2SZ;
  P.semf = semf; P.synf = synf;
  P.w1t_sem = w1t_sem; P.w1t_syn = w1t_syn;
  P.w2t_sem = w2t_sem; P.w2t_syn = w2t_syn;

  const int total = 2 * W1SZ + 2 * W2SZ;
  prep_all<<<(total + 255) / 256, 256, 0, stream>>>(
      sem_W1n, sem_W1s, syn_W1n, syn_W1s,
      sem_W2s, sem_W2n, syn_W2s, syn_W2n,
      w1t_sem, w1t_syn, w2t_sem, w2t_syn);

  sage_kernel<<<2 * NS, 256, 0, stream>>>(P);
  cls_kernel<<<NS / 32, 128, 0, stream>>>(semf, synf, hsg, cls_w1, cls_b1,
                                          cls_w2, cls_b2, (float*)d_out);
}

// Round 7
// 768.919 us; speedup vs baseline: 2.6769x; 2.6769x over previous
//
#include <hip/hip_runtime.h>

#define NS 8192
#define L  50

typedef unsigned short u16;
typedef unsigned int   u32;
typedef __attribute__((ext_vector_type(8))) __bf16 bf16x8;
typedef __attribute__((ext_vector_type(4))) float  f32x4;

// ---------------- LDS layout (bytes) ----------------
// X [64][328] bf16 lives P1..GEMM1 (dies at S4). Tt [160][68] aliases X.
// T2t [64][68] aliases Tt (GEMM2). red aliases Tt tail (post-S7).
// H1 [64][168] at 21760. M (stride 72) at 43264; diag aliases M region.
#define OFF_X    0
#define OFF_TT   0
#define OFF_T2T  0
#define OFF_RED  9216     // red f32 [64][20] = 5120 -> 14336 (Tt dead by then)
#define OFF_H1   21760    // H1 bf16 [64][168] = 21504 -> 43264
#define OFF_M    43264    // M bf16 [64][72] = 9216 -> 52480
#define OFF_DIAG 43264    // diag f32[64] (dead before M written)
#define OFF_WID  52480
#define OFF_CLO  52736
#define OFF_CHI  52992
#define OFF_RDEG 53248
#define SMEM_SZ  53504    // 3 blocks/CU

#define XSTR  328   // 656B rows: ==4 mod 32 dword-banks -> 2-way (free)
#define TSTR  68    // 136B rows, 8B aligned
#define H1STR 168   // 336B rows, 16B aligned
#define MSTR  72    // 144B rows, 16B aligned -> b128 frag loads
#define RSTR  20    // red row stride (f32)

// padded weight tables in ws
#define W1_ROWS 320   // rows [0,10)=W1n tiles t0..t9; [10,20)=W1s tiles s0..s9
#define W1_KP   328
#define W2_ROWS 128
#define W2_KP   168
#define W1SZ (W1_ROWS * W1_KP)
#define W2SZ (W2_ROWS * W2_KP)

__device__ __forceinline__ u16 f2bf(float f) {
  u32 u = __float_as_uint(f);
  u += 0x7fffu + ((u >> 16) & 1u);   // RNE
  return (u16)(u >> 16);
}
__device__ __forceinline__ f32x4 mfma16(bf16x8 a, bf16x8 b, f32x4 c) {
  return __builtin_amdgcn_mfma_f32_16x16x32_bf16(a, b, c, 0, 0, 0);
}
__device__ __forceinline__ uint2 pack4bf(f32x4 c) {
  uint2 p;
  p.x = (u32)f2bf(c[0]) | ((u32)f2bf(c[1]) << 16);
  p.y = (u32)f2bf(c[2]) | ((u32)f2bf(c[3]) << 16);
  return p;
}
union BF8U { bf16x8 v; uint4 u; };
__device__ __forceinline__ bf16x8 ld_bf8_b64pair(const u16* p) {
  uint2 a = *(const uint2*)p;
  uint2 b = *(const uint2*)(p + 4);
  BF8U r; r.u = make_uint4(a.x, a.y, b.x, b.y);
  return r.v;
}

struct GParams {
  const int* words; const int* syn_words; const int* syn_adj;
  const float* embed;
  const float* sem_b1; const float* sem_b2; const float* sem_gw; const float* sem_gb;
  const float* syn_b1; const float* syn_b2; const float* syn_gw; const float* syn_gb;
  const u16* w1t_sem; const u16* w1t_syn; const u16* w2t_sem; const u16* w2t_syn;
  float* semf; float* synf;
};

// agg1 slot: s-tile GT aggregated from Tt tile GT, fused epilogue -> H1
#define AGG_SLOT(ACCSLOT, GT)                                                \
  {                                                                          \
    const int gg = (GT);                                                     \
    const u16* tb = tt + (gg * 16 + ln) * TSTR + quad * 8;                   \
    bf16x8 ta0 = ld_bf8_b64pair(tb);                                         \
    bf16x8 ta1 = ld_bf8_b64pair(tb + 32);                                    \
    f32x4 gacc[4] = {z4, z4, z4, z4};                                        \
    _Pragma("unroll")                                                        \
    for (int vt = 0; vt < 4; ++vt) {                                         \
      gacc[vt] = mfma16(ta0, mb0[vt], gacc[vt]);                             \
      gacc[vt] = mfma16(ta1, mb1[vt], gacc[vt]);                             \
    }                                                                        \
    const int j0 = gg * 16 + quad * 4;                                       \
    float bv[4];                                                             \
    _Pragma("unroll")                                                        \
    for (int r = 0; r < 4; ++r) { int j = j0 + r; bv[r] = (j < 150) ? b1g[j] : 0.f; } \
    _Pragma("unroll")                                                        \
    for (int vt = 0; vt < 4; ++vt) {                                         \
      const int v = vt * 16 + ln;                                            \
      f32x4 hv;                                                              \
      _Pragma("unroll")                                                      \
      for (int r = 0; r < 4; ++r)                                            \
        hv[r] = fmaxf(ACCSLOT[vt][r] + gacc[vt][r] * rd[vt] + bv[r], 0.f);   \
      *(uint2*)(h1p + v * H1STR + j0) = pack4bf(hv);                         \
    }                                                                        \
  }

// One block per (sentence, graph). [0,NS)=semantic, [NS,2NS)=syntax.
__global__ __launch_bounds__(256, 3) void sage_kernel(GParams P) {
  __shared__ __align__(16) char smem[SMEM_SZ];
  int*   wid   = (int*)(smem + OFF_WID);
  u32*   clo   = (u32*)(smem + OFF_CLO);
  u32*   chi   = (u32*)(smem + OFF_CHI);
  float* rdegp = (float*)(smem + OFF_RDEG);
  float* diag  = (float*)(smem + OFF_DIAG);

  const int tid  = threadIdx.x;
  const int lane = tid & 63;
  const int w    = tid >> 6;
  const int ln   = lane & 15;
  const int quad = lane >> 4;

  const bool semg = (blockIdx.x < NS);
  const int  n    = semg ? blockIdx.x : (blockIdx.x - NS);

  const int*   wsrc = semg ? P.words   : P.syn_words;
  const u16*   W1T  = semg ? P.w1t_sem : P.w1t_syn;
  const u16*   W2T  = semg ? P.w2t_sem : P.w2t_syn;
  const float* b1g  = semg ? P.sem_b1  : P.syn_b1;
  const float* b2g  = semg ? P.sem_b2  : P.syn_b2;
  const float* gw   = semg ? P.sem_gw  : P.syn_gw;
  const float* gb   = semg ? P.sem_gb  : P.syn_gb;
  float* featout    = semg ? P.semf    : P.synf;

  // ---- P1: gather X bf16 [64][328] + wid + mask init (one phase) ----
  {
    int wd = 0;
    {
      const int v = w + 4 * ln;
      if (lane < 16 && v < L) wd = wsrc[(size_t)n * L + v];
    }
    for (int i = 0; i < 16; ++i) {
      const int v = w + 4 * i;
      const int word = __shfl(wd, i);
      const float* src = P.embed + (size_t)word * 300;
      u16* xrow = (u16*)(smem + OFF_X) + v * XSTR;
      for (int l = lane; l < 82; l += 64) {
        uint2 pk = make_uint2(0u, 0u);
        if (word > 0 && l < 75) {
          float4 f = *(const float4*)(src + l * 4);
          u32 ax = __float_as_uint(f.x) + 0x8000u;
          u32 ay = __float_as_uint(f.y) + 0x8000u;
          u32 az = __float_as_uint(f.z) + 0x8000u;
          u32 aw = __float_as_uint(f.w) + 0x8000u;
          pk.x = (ax >> 16) | (ay & 0xffff0000u);
          pk.y = (az >> 16) | (aw & 0xffff0000u);
        }
        *(uint2*)(xrow + l * 4) = pk;
      }
    }
    if (tid < 64) {
      wid[tid] = (tid < L) ? wsrc[(size_t)n * L + tid] : 0;
      clo[tid] = 0u; chi[tid] = 0u;
    }
  }
  __syncthreads();   // S1: X + wid + zeroed masks

  const f32x4 z4 = {0.f, 0.f, 0.f, 0.f};

  // ---- P2: Gram + diag (sem) / ballot masks (syn) ----
  if (semg) {
    f32x4 g[4] = {z4, z4, z4, z4};
    const char* xb = smem + OFF_X;
    const int arow = (w * 16 + ln) * (XSTR * 2) + quad * 16;
    for (int kk = 0; kk < 10; ++kk) {
      bf16x8 a = *(const bf16x8*)(xb + arow + kk * 64);
      #pragma unroll
      for (int nt = 0; nt < 4; ++nt) {
        bf16x8 b = *(const bf16x8*)(xb + (nt * 16 + ln) * (XSTR * 2) + quad * 16 + kk * 64);
        g[nt] = mfma16(a, b, g[nt]);
      }
    }
    {
      const int r = ln - quad * 4;        // diagonal: u==v
      if (r >= 0 && r < 4) {
        #pragma unroll
        for (int nt = 0; nt < 4; ++nt) {
          if (nt == w) {
            float val = (r == 0) ? g[nt][0] : (r == 1) ? g[nt][1]
                      : (r == 2) ? g[nt][2] : g[nt][3];
            diag[w * 16 + ln] = val;
          }
        }
      }
    }
    __syncthreads();   // S2: diag visible
    // threshold with inline rsqrt (no recip phase/barrier)
    {
      const int ubase = w * 16 + quad * 4;
      float ru[4]; int uok[4];
      #pragma unroll
      for (int r = 0; r < 4; ++r) {
        ru[r] = rsqrtf(fmaxf(diag[ubase + r], 1e-12f));
        uok[r] = wid[ubase + r] > 0;
      }
      #pragma unroll
      for (int nt = 0; nt < 4; ++nt) {
        const int v = nt * 16 + ln;
        const float rv = rsqrtf(fmaxf(diag[v], 1e-12f));
        const bool vok = wid[v] > 0;
        u32 nib = 0u;
        #pragma unroll
        for (int r = 0; r < 4; ++r) {
          float c = g[nt][r] * ru[r] * rv;
          if (vok && uok[r] && c > 0.7f) nib |= (1u << r);
        }
        if (nib) {
          if (ubase < 32) atomicOr(&clo[v], nib << ubase);
          else            atomicOr(&chi[v], nib << (ubase - 32));
        }
      }
    }
  } else {
    const int* abase = P.syn_adj + (size_t)n * (L * L);
    for (int v = w; v < L; v += 4) {
      int val = (lane < L) ? abase[lane * L + v] : 0;
      unsigned long long m = __ballot(val != 0);
      if (lane == 0) { clo[v] = (u32)m; chi[v] = (u32)(m >> 32); }
    }
    __syncthreads();   // S2 (keep barrier count uniform per block path)
  }
  __syncthreads();   // S3: masks final

  // ---- P3: rdeg + M[v][u] bf16 build + GEMM1 (balanced 5 slots/wave) ----
  if (tid < 64) {
    int dg = __popc(clo[tid]) + __popc(chi[tid]);
    rdegp[tid] = 1.0f / (float)(dg > 0 ? dg : 1);
  }
  {
    const int v = lane, half = w;
    const u32 src = (half < 2) ? clo[v] : chi[v];
    const int sh = (half & 1) * 16;
    u16* Mrow = (u16*)(smem + OFF_M) + v * MSTR + half * 16;
    #pragma unroll
    for (int c = 0; c < 4; ++c) {
      uint2 pk;
      u32 b0 = (src >> (sh + 4 * c + 0)) & 1u;
      u32 b1 = (src >> (sh + 4 * c + 1)) & 1u;
      u32 b2 = (src >> (sh + 4 * c + 2)) & 1u;
      u32 b3 = (src >> (sh + 4 * c + 3)) & 1u;
      pk.x = (b0 ? 0x3F80u : 0u) | (b1 ? 0x3F800000u : 0u);
      pk.y = (b2 ? 0x3F80u : 0u) | (b3 ? 0x3F800000u : 0u);
      *(uint2*)(Mrow + 4 * c) = pk;
    }
  }

  // slots: 0,1 = t(2w), t(2w+1) ; 2 = w<2 ? t(8+w) : s(6+w) ; 3,4 = s(2w), s(2w+1)
  const int rs0 = (2 * w)     * 16 + ln;
  const int rs1 = (2 * w + 1) * 16 + ln;
  const int rs2 = ((w < 2) ? (8 + w) : (16 + w)) * 16 + ln;
  const int rs3 = (10 + 2 * w) * 16 + ln;
  const int rs4 = (11 + 2 * w) * 16 + ln;
  f32x4 acc[5][4];
  #pragma unroll
  for (int i = 0; i < 5; ++i)
    #pragma unroll
    for (int m = 0; m < 4; ++m) acc[i][m] = z4;
  {
    const char* xb = smem + OFF_X;
    for (int kk = 0; kk < 10; ++kk) {
      const int wo = kk * 32 + quad * 8;
      bf16x8 x[4];
      #pragma unroll
      for (int m = 0; m < 4; ++m)
        x[m] = *(const bf16x8*)(xb + (m * 16 + ln) * (XSTR * 2) + quad * 16 + kk * 64);
      bf16x8 bf0 = *(const bf16x8*)(W1T + (size_t)rs0 * W1_KP + wo);
      bf16x8 bf1 = *(const bf16x8*)(W1T + (size_t)rs1 * W1_KP + wo);
      bf16x8 bf2 = *(const bf16x8*)(W1T + (size_t)rs2 * W1_KP + wo);
      bf16x8 bf3 = *(const bf16x8*)(W1T + (size_t)rs3 * W1_KP + wo);
      bf16x8 bf4 = *(const bf16x8*)(W1T + (size_t)rs4 * W1_KP + wo);
      #pragma unroll
      for (int m = 0; m < 4; ++m) {
        acc[0][m] = mfma16(x[m], bf0, acc[0][m]);   // t: D[v][j]
        acc[1][m] = mfma16(x[m], bf1, acc[1][m]);
        acc[3][m] = mfma16(bf3, x[m], acc[3][m]);   // s: D[j][v]
        acc[4][m] = mfma16(bf4, x[m], acc[4][m]);
      }
      if (w < 2) {
        #pragma unroll
        for (int m = 0; m < 4; ++m) acc[2][m] = mfma16(x[m], bf2, acc[2][m]);
      } else {
        #pragma unroll
        for (int m = 0; m < 4; ++m) acc[2][m] = mfma16(bf2, x[m], acc[2][m]);
      }
    }
  }
  __syncthreads();   // S4: X dead; M/rdeg visible

  float rd[4];
  #pragma unroll
  for (int vt = 0; vt < 4; ++vt) rd[vt] = rdegp[vt * 16 + ln];

  // ---- P4: Tt writes (each wave its own t-tiles) ----
  {
    u16* tt = (u16*)(smem + OFF_TT);
    #pragma unroll
    for (int m = 0; m < 4; ++m) {
      const int v0 = m * 16 + quad * 4;
      *(uint2*)(tt + ((2 * w)     * 16 + ln) * TSTR + v0) = pack4bf(acc[0][m]);
      *(uint2*)(tt + ((2 * w + 1) * 16 + ln) * TSTR + v0) = pack4bf(acc[1][m]);
    }
    if (w < 2) {
      #pragma unroll
      for (int m = 0; m < 4; ++m) {
        const int v0 = m * 16 + quad * 4;
        *(uint2*)(tt + ((8 + w) * 16 + ln) * TSTR + v0) = pack4bf(acc[2][m]);
      }
    }
  }
  __syncthreads();   // S5: Tt visible

  // ---- P5: agg1 = Tt x M (all waves, 2-3 slots each); epilogue -> H1 ----
  {
    const u16* tt = (const u16*)(smem + OFF_TT);
    const u16* Mp = (const u16*)(smem + OFF_M);
    u16* h1p = (u16*)(smem + OFF_H1);
    bf16x8 mb0[4], mb1[4];
    #pragma unroll
    for (int vt = 0; vt < 4; ++vt) {
      mb0[vt] = *(const bf16x8*)(Mp + (vt * 16 + ln) * MSTR + quad * 8);
      mb1[vt] = *(const bf16x8*)(Mp + (vt * 16 + ln) * MSTR + quad * 8 + 32);
    }
    AGG_SLOT(acc[3], 2 * w)
    AGG_SLOT(acc[4], 2 * w + 1)
    if (w >= 2) AGG_SLOT(acc[2], 6 + w)
  }
  __syncthreads();   // S6: all H1 written

  // ---- P6: GEMM2 (s2 swapped in regs; t2 -> T2t self rows) + agg2 ----
  f32x4 h2v[4];
  {
    f32x4 s2acc[4] = {z4, z4, z4, z4};
    f32x4 t2acc[4] = {z4, z4, z4, z4};
    const u16* h1p = (const u16*)(smem + OFF_H1);
    for (int kk = 0; kk < 5; ++kk) {
      const int wo = kk * 32 + quad * 8;
      bf16x8 h[4];
      #pragma unroll
      for (int t4 = 0; t4 < 4; ++t4)
        h[t4] = *(const bf16x8*)(h1p + (t4 * 16 + ln) * H1STR + wo);
      bf16x8 a2  = *(const bf16x8*)(W2T + (size_t)(w * 16 + ln) * W2_KP + wo);
      bf16x8 b2f = *(const bf16x8*)(W2T + (size_t)((4 + w) * 16 + ln) * W2_KP + wo);
      #pragma unroll
      for (int vt = 0; vt < 4; ++vt) {
        s2acc[vt] = mfma16(a2, h[vt], s2acc[vt]);   // D[j2][v]
        t2acc[vt] = mfma16(h[vt], b2f, t2acc[vt]);  // D[v][j2]
      }
    }
    u16* t2t = (u16*)(smem + OFF_T2T);
    #pragma unroll
    for (int m = 0; m < 4; ++m) {
      const int v0 = m * 16 + quad * 4;
      *(uint2*)(t2t + (w * 16 + ln) * TSTR + v0) = pack4bf(t2acc[m]);
    }
    // agg2: A = T2t (self rows, wave-synchronous), B = M (phase-local frags)
    const u16* Mp = (const u16*)(smem + OFF_M);
    f32x4 g2[4] = {z4, z4, z4, z4};
    const u16* t2b = t2t + (w * 16 + ln) * TSTR + quad * 8;
    bf16x8 u0 = ld_bf8_b64pair(t2b);
    bf16x8 u1 = ld_bf8_b64pair(t2b + 32);
    #pragma unroll
    for (int vt = 0; vt < 4; ++vt) {
      bf16x8 m0 = *(const bf16x8*)(Mp + (vt * 16 + ln) * MSTR + quad * 8);
      bf16x8 m1 = *(const bf16x8*)(Mp + (vt * 16 + ln) * MSTR + quad * 8 + 32);
      g2[vt] = mfma16(u0, m0, g2[vt]);
      g2[vt] = mfma16(u1, m1, g2[vt]);
    }
    const int j0q = w * 16 + quad * 4;
    float b2v[4];
    #pragma unroll
    for (int r = 0; r < 4; ++r) b2v[r] = b2g[j0q + r];
    #pragma unroll
    for (int vt = 0; vt < 4; ++vt)
      #pragma unroll
      for (int r = 0; r < 4; ++r)
        h2v[vt][r] = s2acc[vt][r] + g2[vt][r] * rd[vt] + b2v[r];
  }
  __syncthreads();   // S7: Tt/T2t/H1 reads done -> red region free

  // ---- P7: gate partials -> red[v][RSTR] ----
  {
    const int j0q = w * 16 + quad * 4;
    float gwv[4];
    #pragma unroll
    for (int r = 0; r < 4; ++r) gwv[r] = gw[j0q + r];
    float* redp = (float*)(smem + OFF_RED);
    #pragma unroll
    for (int vt = 0; vt < 4; ++vt) {
      float p = h2v[vt][0] * gwv[0] + h2v[vt][1] * gwv[1]
              + h2v[vt][2] * gwv[2] + h2v[vt][3] * gwv[3];
      redp[(vt * 16 + ln) * RSTR + (w * 4 + quad)] = p;
    }
  }
  __syncthreads();   // S8

  // ---- P8: masked softmax, redundant per wave (registers, no barrier) ----
  float attnv;
  {
    const float* redp = (const float*)(smem + OFF_RED) + lane * RSTR;
    f32x4 r0 = *(const f32x4*)(redp);
    f32x4 r1 = *(const f32x4*)(redp + 4);
    f32x4 r2 = *(const f32x4*)(redp + 8);
    f32x4 r3 = *(const f32x4*)(redp + 12);
    float g = gb[0] + r0[0] + r0[1] + r0[2] + r0[3] + r1[0] + r1[1] + r1[2] + r1[3]
            + r2[0] + r2[1] + r2[2] + r2[3] + r3[0] + r3[1] + r3[2] + r3[3];
    const bool val = wid[lane] > 0;
    g = val ? g : -1e30f;
    float mx = g;
    #pragma unroll
    for (int off = 32; off; off >>= 1) mx = fmaxf(mx, __shfl_xor(mx, off));
    float e = val ? __expf(g - mx) : 0.f;
    float ssum = e;
    #pragma unroll
    for (int off = 32; off; off >>= 1) ssum += __shfl_xor(ssum, off);
    attnv = e / ssum;
  }

  // ---- P9: pooled feature out[j2] = sum_v attn[v] h2[v][j2] ----
  {
    float av[4];
    #pragma unroll
    for (int vt = 0; vt < 4; ++vt) av[vt] = __shfl(attnv, vt * 16 + ln);
    float xr[4];
    #pragma unroll
    for (int r = 0; r < 4; ++r) {
      float x = av[0] * h2v[0][r] + av[1] * h2v[1][r]
              + av[2] * h2v[2][r] + av[3] * h2v[3][r];
      #pragma unroll
      for (int off = 1; off < 16; off <<= 1) x += __shfl_xor(x, off);
      xr[r] = x;
    }
    if (ln == 0) {
      const int j0q = w * 16 + quad * 4;
      *(float4*)(featout + (size_t)n * 64 + j0q) = make_float4(xr[0], xr[1], xr[2], xr[3]);
    }
  }
}

// ---------------- merged weight prep: one launch for all 4 tables ----------------
__global__ void prep_all(const float* sem_W1n, const float* sem_W1s,
                         const float* syn_W1n, const float* syn_W1s,
                         const float* sem_W2s, const float* sem_W2n,
                         const float* syn_W2s, const float* syn_W2n,
                         u16* w1t_sem, u16* w1t_syn, u16* w2t_sem, u16* w2t_syn) {
  int idx = blockIdx.x * 256 + threadIdx.x;
  if (idx < 2 * W1SZ) {
    const bool sem = idx < W1SZ;
    const int li = sem ? idx : idx - W1SZ;
    const float* Wn = sem ? sem_W1n : syn_W1n;
    const float* Ws = sem ? sem_W1s : syn_W1s;
    u16* dst = sem ? w1t_sem : w1t_syn;
    int nn = li / W1_KP, k = li - nn * W1_KP;
    float v = 0.f;
    if (k < 300) {
      if (nn < 150) v = Wn[k * 150 + nn];
      else if (nn >= 160 && nn < 310) v = Ws[k * 150 + (nn - 160)];
    }
    dst[li] = f2bf(v);
  } else if (idx < 2 * W1SZ + 2 * W2SZ) {
    int j = idx - 2 * W1SZ;
    const bool sem = j < W2SZ;
    const int li = sem ? j : j - W2SZ;
    const float* Ws = sem ? sem_W2s : syn_W2s;
    const float* Wn = sem ? sem_W2n : syn_W2n;
    u16* dst = sem ? w2t_sem : w2t_syn;
    int nn = li / W2_KP, k = li - nn * W2_KP;
    float v = 0.f;
    if (k < 150) v = (nn < 64) ? Ws[k * 64 + nn] : Wn[k * 64 + (nn - 64)];
    dst[li] = f2bf(v);
  }
}

// ---------------- classifier: 16 rows/block, 512 blocks ----------------
__global__ __launch_bounds__(128) void cls_kernel(const float* semf, const float* synf,
                                                  const float* hsg,
                                                  const float* w1, const float* b1,
                                                  const float* w2, const float* b2,
                                                  float* out) {
  __shared__ float feat[16][192];
  __shared__ float hid[16][132];
  const int r0 = blockIdx.x * 16;
  for (int idx = threadIdx.x; idx < 16 * 192; idx += 128) {
    int r = idx / 192, c = idx % 192;
    float v;
    if (c < 64)        v = semf[(size_t)(r0 + r) * 64 + c];
    else if (c < 128)  v = synf[(size_t)(r0 + r) * 64 + (c - 64)];
    else               v = hsg [(size_t)(r0 + r) * 64 + (c - 128)];
    feat[r][c] = v;
  }
  __syncthreads();
  {
    const int j = threadIdx.x;
    float acc[16];
    float bb = b1[j];
    #pragma unroll
    for (int r = 0; r < 16; ++r) acc[r] = bb;
    for (int k = 0; k < 192; ++k) {
      float ww = w1[(size_t)k * 128 + j];
      #pragma unroll
      for (int r = 0; r < 16; ++r) acc[r] += feat[r][k] * ww;
    }
    #pragma unroll
    for (int r = 0; r < 16; ++r) hid[r][j] = fmaxf(acc[r], 0.0f);
  }
  __syncthreads();
  if (threadIdx.x < 32) {
    const int r = threadIdx.x >> 1, o = threadIdx.x & 1;
    float a = b2[o];
    for (int h = 0; h < 128; ++h) a += hid[r][h] * w2[h * 2 + o];
    out[(size_t)(r0 + r) * 2 + o] = a;
  }
}

extern "C" void kernel_launch(void* const* d_in, const int* in_sizes, int n_in,
                              void* d_out, int out_size, void* d_ws, size_t ws_size,
                              hipStream_t stream) {
  GParams P;
  P.words     = (const int*)d_in[0];
  P.syn_words = (const int*)d_in[1];
  P.syn_adj   = (const int*)d_in[2];
  const float* hsg = (const float*)d_in[3];
  P.embed   = (const float*)d_in[4];
  const float* sem_W1s = (const float*)d_in[5];
  const float* sem_W1n = (const float*)d_in[6];
  P.sem_b1  = (const float*)d_in[7];
  const float* sem_W2s = (const float*)d_in[8];
  const float* sem_W2n = (const float*)d_in[9];
  P.sem_b2  = (const float*)d_in[10];
  P.sem_gw  = (const float*)d_in[11];
  P.sem_gb  = (const float*)d_in[12];
  const float* syn_W1s = (const float*)d_in[13];
  const float* syn_W1n = (const float*)d_in[14];
  P.syn_b1  = (const float*)d_in[15];
  const float* syn_W2s = (const float*)d_in[16];
  const float* syn_W2n = (const float*)d_in[17];
  P.syn_b2  = (const float*)d_in[18];
  P.syn_gw  = (const float*)d_in[19];
  P.syn_gb  = (const float*)d_in[20];
  const float* cls_w1 = (const float*)d_in[21];
  const float* cls_b1 = (const float*)d_in[22];
  const float* cls_w2 = (const float*)d_in[23];
  const float* cls_b2 = (const float*)d_in[24];

  float* semf = (float*)d_ws;                       // [NS][64]
  float* synf = semf + (size_t)NS * 64;             // [NS][64]  (4 MB total)
  u16* w1t_sem = (u16*)((char*)d_ws + (size_t)4 * 1024 * 1024);
  u16* w1t_syn = w1t_sem + W1SZ;
  u16* w2t_sem = w1t_syn + W1SZ;
  u16* w2t_syn = w2t_sem + W2SZ;
  P.semf = semf; P.synf = synf;
  P.w1t_sem = w1t_sem; P.w1t_syn = w1t_syn;
  P.w2t_sem = w2t_sem; P.w2t_syn = w2t_syn;

  const int total = 2 * W1SZ + 2 * W2SZ;
  prep_all<<<(total + 255) / 256, 256, 0, stream>>>(
      sem_W1n, sem_W1s, syn_W1n, syn_W1s,
      sem_W2s, sem_W2n, syn_W2s, syn_W2n,
      w1t_sem, w1t_syn, w2t_sem, w2t_syn);

  sage_kernel<<<2 * NS, 256, 0, stream>>>(P);
  cls_kernel<<<NS / 16, 128, 0, stream>>>(semf, synf, hsg, cls_w1, cls_b1,
                                          cls_w2, cls_b2, (float*)d_out);
}